// Round 1
// baseline (73998.285 us; speedup 1.0000x reference)
//
#include <hip/hip_runtime.h>
#include <math.h>

#define Hn 1024
#define Bn 4096
#define INW 33
#define OUTS (Bn * Hn)
#define NBH 128   // blocks per layer group
#define TPB 512   // 8 waves per block -> 8 h-indices per block

__device__ __forceinline__ float sigmoidf_(float x) {
    return 1.0f / (1.0f + __expf(-x));
}
__device__ __forceinline__ float tanhf_(float x) {
    float e = __expf(-2.0f * fabsf(x));
    float r = (1.0f - e) / (1.0f + e);
    return copysignf(r, x);
}

// wave 0 (64 lanes) polls 128 per-block done flags (distinct addresses, no
// atomic RMW contention). Lanes 0-31 cover flags lane, lane+32, lane+64,
// lane+96; lanes 32-63 duplicate (same addresses -> broadcast loads).
__device__ __forceinline__ void wait_done(const int* base, int lane) {
    const int a = lane & 31;
    int iter = 0;
    for (;;) {
        int v0 = __hip_atomic_load(base + a,      __ATOMIC_ACQUIRE, __HIP_MEMORY_SCOPE_AGENT);
        int v1 = __hip_atomic_load(base + a + 32, __ATOMIC_ACQUIRE, __HIP_MEMORY_SCOPE_AGENT);
        int v2 = __hip_atomic_load(base + a + 64, __ATOMIC_ACQUIRE, __HIP_MEMORY_SCOPE_AGENT);
        int v3 = __hip_atomic_load(base + a + 96, __ATOMIC_ACQUIRE, __HIP_MEMORY_SCOPE_AGENT);
        bool ok = (v0 != 0) && (v1 != 0) && (v2 != 0) && (v3 != 0);
        if (__all(ok)) break;
        __builtin_amdgcn_s_sleep(1);
        if (++iter > (1 << 24)) break;  // bailout: wrong answer beats a wedged GPU
    }
}

// Build xin = [x | ip_emb[ip] | port_emb[port]] (4096 x 33) and zero the done
// flag arrays (ws is re-poisoned to 0xAA before every replay).
__global__ void prep_kernel(const float* __restrict__ x, const int* __restrict__ ip,
                            const int* __restrict__ port, const float* __restrict__ ip_emb,
                            const float* __restrict__ port_emb,
                            float* __restrict__ xin, int* __restrict__ donez) {
    int gid = blockIdx.x * blockDim.x + threadIdx.x;
    if (gid < Bn * INW) {
        int t = gid / INW;
        int k = gid - t * INW;
        float v;
        if (k < 17) {
            v = x[t * 17 + k];
        } else if (k < 25) {
            v = ip_emb[ip[t * 8 + (k - 17)]];       // ip_emb is (256,1)
        } else {
            int kk = k - 25;
            int q = kk >> 2, r = kk & 3;
            v = port_emb[port[t * 2 + q] * 4 + r];  // port_emb is (70000,4)
        }
        xin[gid] = v;
    }
    if (gid < 2 * Bn * NBH) donez[gid] = 0;  // done0 then done1, contiguous
}

__global__ void __launch_bounds__(TPB, 2) lstm_kernel(
    const float* __restrict__ xin,
    const float* __restrict__ hid0, const float* __restrict__ cel0,
    const float* __restrict__ Wih0, const float* __restrict__ Whh0,
    const float* __restrict__ bih0, const float* __restrict__ bhh0,
    const float* __restrict__ Wih1, const float* __restrict__ Whh1,
    const float* __restrict__ bih1, const float* __restrict__ bhh1,
    float* __restrict__ out,
    float* __restrict__ h0hist, float* __restrict__ h1hist,
    int* __restrict__ done0, int* __restrict__ done1)
{
    __shared__ float hs[2 * Hn];
    const int tid  = threadIdx.x;
    const int lane = tid & 63;
    const int wave = tid >> 6;
    const int bx   = blockIdx.x;

    if (bx < NBH) {
        // ================= layer 0 group =================
        const int blk = bx;
        const int j   = blk * 8 + wave;   // this wave owns h-index j
        float w[4][16], wx[4], bs[4];
#pragma unroll
        for (int g = 0; g < 4; ++g) {
            const int row = j + Hn * g;   // gate order i,f,g,o
            const float* wr = Whh0 + (size_t)row * Hn;
#pragma unroll
            for (int i = 0; i < 16; ++i) w[g][i] = wr[lane + 64 * i];
            wx[g] = (lane < INW) ? Wih0[row * INW + lane] : 0.0f;
            bs[g] = bih0[row] + bhh0[row];
        }
        float c = cel0[j];
        float h = 0.0f;

        for (int t = 0; t < Bn; ++t) {
            if (t > 0 && wave == 0) wait_done(done0 + (t - 1) * NBH, lane);
            __syncthreads();
            if (t == 0) {
                hs[tid]       = hid0[tid];
                hs[tid + 512] = hid0[tid + 512];
            } else {
                hs[tid]       = __hip_atomic_load(h0hist + (size_t)(t - 1) * Hn + tid,       __ATOMIC_RELAXED, __HIP_MEMORY_SCOPE_AGENT);
                hs[tid + 512] = __hip_atomic_load(h0hist + (size_t)(t - 1) * Hn + tid + 512, __ATOMIC_RELAXED, __HIP_MEMORY_SCOPE_AGENT);
            }
            __syncthreads();

            float xv = xin[t * INW + (lane < INW ? lane : 0)];
            float a0 = wx[0] * xv, a1 = wx[1] * xv, a2 = wx[2] * xv, a3 = wx[3] * xv;
#pragma unroll
            for (int i = 0; i < 16; ++i) {
                float hv = hs[lane + 64 * i];   // bank = lane%32: 2-way, free
                a0 += w[0][i] * hv; a1 += w[1][i] * hv;
                a2 += w[2][i] * hv; a3 += w[3][i] * hv;
            }
#pragma unroll
            for (int off = 32; off >= 1; off >>= 1) {
                a0 += __shfl_xor(a0, off); a1 += __shfl_xor(a1, off);
                a2 += __shfl_xor(a2, off); a3 += __shfl_xor(a3, off);
            }
            float gi = sigmoidf_(a0 + bs[0]);
            float gf = sigmoidf_(a1 + bs[1]);
            float gg = tanhf_   (a2 + bs[2]);
            float go = sigmoidf_(a3 + bs[3]);
            c = gf * c + gi * gg;
            h = go * tanhf_(c);
            if (lane == 0)
                __hip_atomic_store(h0hist + (size_t)t * Hn + j, h, __ATOMIC_RELAXED, __HIP_MEMORY_SCOPE_AGENT);
            __syncthreads();  // drains all waves' h stores (s_waitcnt vmcnt(0) before s_barrier)
            if (tid == 0)
                __hip_atomic_store(done0 + t * NBH + blk, 1, __ATOMIC_RELEASE, __HIP_MEMORY_SCOPE_AGENT);
        }
        if (lane == 0) {
            out[OUTS + j] = h;            // hf layer 0
            out[OUTS + 2 * Hn + j] = c;   // cf layer 0
        }
    } else {
        // ================= layer 1 group =================
        const int blk = bx - NBH;
        const int j   = blk * 8 + wave;
        float w[4][32], bs[4];
#pragma unroll
        for (int g = 0; g < 4; ++g) {
            const int row = j + Hn * g;
            const float* wr1 = Wih1 + (size_t)row * Hn;
            const float* wr2 = Whh1 + (size_t)row * Hn;
#pragma unroll
            for (int i = 0; i < 16; ++i) {
                w[g][i]      = wr1[lane + 64 * i];   // cols of h0[t]
                w[g][16 + i] = wr2[lane + 64 * i];   // cols of h1[t-1]
            }
            bs[g] = bih1[row] + bhh1[row];
        }
        float c = cel0[Hn + j];
        float h = 0.0f;

        for (int t = 0; t < Bn; ++t) {
            if (wave == 0) {
                wait_done(done0 + t * NBH, lane);               // need h0[t]
                if (t > 0) wait_done(done1 + (t - 1) * NBH, lane); // need h1[t-1]
            }
            __syncthreads();
            hs[tid]       = __hip_atomic_load(h0hist + (size_t)t * Hn + tid,       __ATOMIC_RELAXED, __HIP_MEMORY_SCOPE_AGENT);
            hs[tid + 512] = __hip_atomic_load(h0hist + (size_t)t * Hn + tid + 512, __ATOMIC_RELAXED, __HIP_MEMORY_SCOPE_AGENT);
            if (t == 0) {
                hs[Hn + tid]       = hid0[Hn + tid];
                hs[Hn + tid + 512] = hid0[Hn + tid + 512];
            } else {
                hs[Hn + tid]       = __hip_atomic_load(h1hist + (size_t)(t - 1) * Hn + tid,       __ATOMIC_RELAXED, __HIP_MEMORY_SCOPE_AGENT);
                hs[Hn + tid + 512] = __hip_atomic_load(h1hist + (size_t)(t - 1) * Hn + tid + 512, __ATOMIC_RELAXED, __HIP_MEMORY_SCOPE_AGENT);
            }
            __syncthreads();

            float a0 = 0.f, a1 = 0.f, a2 = 0.f, a3 = 0.f;
#pragma unroll
            for (int i = 0; i < 32; ++i) {
                float hv = hs[lane + 64 * i];
                a0 += w[0][i] * hv; a1 += w[1][i] * hv;
                a2 += w[2][i] * hv; a3 += w[3][i] * hv;
            }
#pragma unroll
            for (int off = 32; off >= 1; off >>= 1) {
                a0 += __shfl_xor(a0, off); a1 += __shfl_xor(a1, off);
                a2 += __shfl_xor(a2, off); a3 += __shfl_xor(a3, off);
            }
            float gi = sigmoidf_(a0 + bs[0]);
            float gf = sigmoidf_(a1 + bs[1]);
            float gg = tanhf_   (a2 + bs[2]);
            float go = sigmoidf_(a3 + bs[3]);
            c = gf * c + gi * gg;
            h = go * tanhf_(c);
            if (lane == 0)
                __hip_atomic_store(h1hist + (size_t)t * Hn + j, h, __ATOMIC_RELAXED, __HIP_MEMORY_SCOPE_AGENT);
            if (lane == 1)
                out[(size_t)t * Hn + j] = fmaxf(h, 0.0f);   // outputs[t] = relu(h1)
            __syncthreads();
            if (tid == 0)
                __hip_atomic_store(done1 + t * NBH + blk, 1, __ATOMIC_RELEASE, __HIP_MEMORY_SCOPE_AGENT);
        }
        if (lane == 0) {
            out[OUTS + Hn + j] = h;           // hf layer 1
            out[OUTS + 3 * Hn + j] = c;       // cf layer 1
        }
    }
}

extern "C" void kernel_launch(void* const* d_in, const int* in_sizes, int n_in,
                              void* d_out, int out_size, void* d_ws, size_t ws_size,
                              hipStream_t stream) {
    const float* x        = (const float*)d_in[0];
    const int*   ip       = (const int*)d_in[1];
    const int*   port     = (const int*)d_in[2];
    const float* hidden   = (const float*)d_in[3];
    const float* cell     = (const float*)d_in[4];
    const float* ip_emb   = (const float*)d_in[5];
    const float* port_emb = (const float*)d_in[6];
    const float* Wih0     = (const float*)d_in[7];
    const float* Whh0     = (const float*)d_in[8];
    const float* bih0     = (const float*)d_in[9];
    const float* bhh0     = (const float*)d_in[10];
    const float* Wih1     = (const float*)d_in[11];
    const float* Whh1     = (const float*)d_in[12];
    const float* bih1     = (const float*)d_in[13];
    const float* bhh1     = (const float*)d_in[14];
    float* out = (float*)d_out;

    // ws layout: xin (4096x33) | h0hist (4096x1024) | h1hist (4096x1024) |
    //            done0 (4096x128 int) | done1 (4096x128 int)   ~= 38.3 MB
    float* xin    = (float*)d_ws;
    float* h0hist = xin + Bn * INW;
    float* h1hist = h0hist + (size_t)Bn * Hn;
    int*   done0  = (int*)(h1hist + (size_t)Bn * Hn);
    int*   done1  = done0 + Bn * NBH;

    int prep_elems = 2 * Bn * NBH;  // covers flag zeroing (largest range)
    prep_kernel<<<dim3((prep_elems + 255) / 256), dim3(256), 0, stream>>>(
        x, ip, port, ip_emb, port_emb, xin, done0);

    lstm_kernel<<<dim3(2 * NBH), dim3(TPB), 0, stream>>>(
        xin, hidden, cell, Wih0, Whh0, bih0, bhh0, Wih1, Whh1, bih1, bhh1,
        out, h0hist, h1hist, done0, done1);
}

// Round 2
// 23139.452 us; speedup vs baseline: 3.1979x; 3.1979x over previous
//
#include <hip/hip_runtime.h>
#include <hip/hip_fp16.h>
#include <math.h>

#define Hn 1024
#define Bn 4096
#define INW 33
#define OUTS (Bn * Hn)
#define TPB 512

typedef _Float16 half2v __attribute__((ext_vector_type(2)));

__device__ __forceinline__ float sigmoidf_(float x) {
    return 1.0f / (1.0f + __expf(-x));
}
__device__ __forceinline__ float tanhf_(float x) {
    float e = __expf(-2.0f * fabsf(x));
    float r = (1.0f - e) / (1.0f + e);
    return copysignf(r, x);
}
__device__ __forceinline__ unsigned pack2(float a, float b) {
    __half2 h = __floats2half2_rn(a, b);
    return __builtin_bit_cast(unsigned, h);
}
__device__ __forceinline__ float dot2acc(unsigned w, unsigned hv, float acc) {
#if __has_builtin(__builtin_amdgcn_fdot2)
    return __builtin_amdgcn_fdot2(__builtin_bit_cast(half2v, w),
                                  __builtin_bit_cast(half2v, hv), acc, false);
#else
    __half2 wh = __builtin_bit_cast(__half2, w);
    __half2 hh = __builtin_bit_cast(__half2, hv);
    float2 wf = __half22float2(wh), hf = __half22float2(hh);
    return acc + wf.x * hf.x + wf.y * hf.y;
#endif
}

// Spin on one self-validating packet: u64 = (tag<<32) | half2-data.
// Relaxed agent-scope atomic load bypasses L1 (sc1) -> always sees LLC.
// No fence needed: data rides in the same 8-byte atom as the tag.
__device__ __forceinline__ unsigned poll_pkt(const unsigned long long* p, unsigned tag) {
    unsigned long long v;
    int it = 0;
    do {
        v = __hip_atomic_load(p, __ATOMIC_RELAXED, __HIP_MEMORY_SCOPE_AGENT);
        if (++it > (1 << 26)) break;  // bailout: wrong answer beats a wedged GPU
    } while ((unsigned)(v >> 32) != tag);
    return (unsigned)v;
}

// xin = [x | ip_emb[ip] | port_emb[port]]  (4096 x 33)
__global__ void prep_kernel(const float* __restrict__ x, const int* __restrict__ ip,
                            const int* __restrict__ port, const float* __restrict__ ip_emb,
                            const float* __restrict__ port_emb, float* __restrict__ xin) {
    int gid = blockIdx.x * blockDim.x + threadIdx.x;
    if (gid < Bn * INW) {
        int t = gid / INW;
        int k = gid - t * INW;
        float v;
        if (k < 17) {
            v = x[t * 17 + k];
        } else if (k < 25) {
            v = ip_emb[ip[t * 8 + (k - 17)]];
        } else {
            int kk = k - 25;
            v = port_emb[port[t * 2 + (kk >> 2)] * 4 + (kk & 3)];
        }
        xin[gid] = v;
    }
}

__global__ void __launch_bounds__(TPB, 2) lstm_kernel(
    const float* __restrict__ xin,
    const float* __restrict__ hid0, const float* __restrict__ cel0,
    const float* __restrict__ Wih0, const float* __restrict__ Whh0,
    const float* __restrict__ bih0, const float* __restrict__ bhh0,
    const float* __restrict__ Wih1, const float* __restrict__ Whh1,
    const float* __restrict__ bih1, const float* __restrict__ bhh1,
    float* __restrict__ out,
    unsigned long long* __restrict__ h0pkt,   // [4096][512] : tag|h0 pair
    unsigned long long* __restrict__ h1pkt)   // [4096][512] : tag|h1 pair
{
    __shared__ unsigned hs2[1024];   // half2 chunks of the input vector(s)
    const int tid  = threadIdx.x;
    const int lane = tid & 63;
    const int wave = tid >> 6;
    const int bx   = blockIdx.x;

    if (bx < 32) {
        // ================= layer 0 : 32 blocks, wave owns 4 h-indices ========
        const int j0 = bx * 32 + wave * 4;
        unsigned w2[4][4][8];     // f16-pair weights of Whh0
        float    wx[4][4];        // fp32 x-weights (lane < 33)
        float    bs[4][4];
#pragma unroll
        for (int jj = 0; jj < 4; ++jj) {
#pragma unroll
            for (int g = 0; g < 4; ++g) {
                const int row = g * Hn + (j0 + jj);
                const float* wr = Whh0 + (size_t)row * Hn;
#pragma unroll
                for (int k = 0; k < 8; ++k) {
                    int c = lane + 64 * k;
                    w2[jj][g][k] = pack2(wr[2 * c], wr[2 * c + 1]);
                }
                wx[jj][g] = (lane < INW) ? Wih0[row * INW + lane] : 0.0f;
                bs[jj][g] = bih0[row] + bhh0[row];
            }
        }
        float cst[4], hcur[4];
#pragma unroll
        for (int jj = 0; jj < 4; ++jj) { cst[jj] = cel0[j0 + jj]; hcur[jj] = 0.0f; }

        for (int t = 0; t < Bn; ++t) {
            float xv = xin[t * INW + (lane < INW ? lane : 0)];  // prefetch (L2-hot)
            unsigned hword;
            if (t == 0) hword = pack2(hid0[2 * tid], hid0[2 * tid + 1]);
            else        hword = poll_pkt(&h0pkt[(size_t)(t - 1) * 512 + tid], (unsigned)t);
            hs2[tid] = hword;
            __syncthreads();

            float acc[4][4];
#pragma unroll
            for (int jj = 0; jj < 4; ++jj)
#pragma unroll
                for (int g = 0; g < 4; ++g) acc[jj][g] = wx[jj][g] * xv;
#pragma unroll
            for (int k = 0; k < 8; ++k) {
                unsigned hv = hs2[lane + 64 * k];   // 2-way bank alias: free
#pragma unroll
                for (int jj = 0; jj < 4; ++jj)
#pragma unroll
                    for (int g = 0; g < 4; ++g)
                        acc[jj][g] = dot2acc(w2[jj][g][k], hv, acc[jj][g]);
            }
            __syncthreads();   // hs2 reads done; next iter may overwrite

#pragma unroll
            for (int off = 32; off >= 1; off >>= 1)
#pragma unroll
                for (int jj = 0; jj < 4; ++jj)
#pragma unroll
                    for (int g = 0; g < 4; ++g)
                        acc[jj][g] += __shfl_xor(acc[jj][g], off);

#pragma unroll
            for (int jj = 0; jj < 4; ++jj) {
                float gi = sigmoidf_(acc[jj][0] + bs[jj][0]);
                float gf = sigmoidf_(acc[jj][1] + bs[jj][1]);
                float gg = tanhf_   (acc[jj][2] + bs[jj][2]);
                float go = sigmoidf_(acc[jj][3] + bs[jj][3]);
                cst[jj] = gf * cst[jj] + gi * gg;
                hcur[jj] = go * tanhf_(cst[jj]);
            }
            if (lane == 0) {
                unsigned long long tw = ((unsigned long long)(t + 1)) << 32;
                __hip_atomic_store(&h0pkt[(size_t)t * 512 + (j0 >> 1)],
                                   tw | pack2(hcur[0], hcur[1]),
                                   __ATOMIC_RELAXED, __HIP_MEMORY_SCOPE_AGENT);
                __hip_atomic_store(&h0pkt[(size_t)t * 512 + (j0 >> 1) + 1],
                                   tw | pack2(hcur[2], hcur[3]),
                                   __ATOMIC_RELAXED, __HIP_MEMORY_SCOPE_AGENT);
            }
        }
        if (lane == 0) {
#pragma unroll
            for (int jj = 0; jj < 4; ++jj) {
                out[OUTS + j0 + jj] = hcur[jj];            // hf layer 0
                out[OUTS + 2 * Hn + j0 + jj] = cst[jj];    // cf layer 0
            }
        }
    } else {
        // ================= layer 1 : 64 blocks, wave owns 2 h-indices ========
        const int blk = bx - 32;
        const int j0  = blk * 16 + wave * 2;
        unsigned w2[2][4][16];    // k<8: Wih1 (vs h0[t]) ; k>=8: Whh1 (vs h1[t-1])
        float    bs[2][4];
#pragma unroll
        for (int jj = 0; jj < 2; ++jj) {
#pragma unroll
            for (int g = 0; g < 4; ++g) {
                const int row = g * Hn + (j0 + jj);
                const float* wr1 = Wih1 + (size_t)row * Hn;
                const float* wr2 = Whh1 + (size_t)row * Hn;
#pragma unroll
                for (int k = 0; k < 8; ++k) {
                    int c = lane + 64 * k;
                    w2[jj][g][k]     = pack2(wr1[2 * c], wr1[2 * c + 1]);
                    w2[jj][g][8 + k] = pack2(wr2[2 * c], wr2[2 * c + 1]);
                }
                bs[jj][g] = bih1[row] + bhh1[row];
            }
        }
        float cst[2], hcur[2];
#pragma unroll
        for (int jj = 0; jj < 2; ++jj) { cst[jj] = cel0[Hn + j0 + jj]; hcur[jj] = 0.0f; }

        for (int t = 0; t < Bn; ++t) {
            // poll both dependencies concurrently (each thread owns 1 packet of each)
            unsigned w0val = 0, w1val = 0;
            bool d0 = false, d1 = false;
            const unsigned long long* p0 = &h0pkt[(size_t)t * 512 + tid];
            const unsigned long long* p1 = &h1pkt[(size_t)(t - 1) * 512 + tid];
            if (t == 0) { w1val = pack2(hid0[Hn + 2 * tid], hid0[Hn + 2 * tid + 1]); d1 = true; }
            int it = 0;
            while (!(d0 && d1)) {
                if (!d0) {
                    unsigned long long v = __hip_atomic_load(p0, __ATOMIC_RELAXED, __HIP_MEMORY_SCOPE_AGENT);
                    if ((unsigned)(v >> 32) == (unsigned)(t + 1)) { w0val = (unsigned)v; d0 = true; }
                }
                if (!d1) {
                    unsigned long long v = __hip_atomic_load(p1, __ATOMIC_RELAXED, __HIP_MEMORY_SCOPE_AGENT);
                    if ((unsigned)(v >> 32) == (unsigned)t) { w1val = (unsigned)v; d1 = true; }
                }
                if (++it > (1 << 26)) break;
            }
            hs2[tid]       = w0val;   // h0[t]   chunks 0..511
            hs2[512 + tid] = w1val;   // h1[t-1] chunks 512..1023
            __syncthreads();

            float acc[2][4];
#pragma unroll
            for (int jj = 0; jj < 2; ++jj)
#pragma unroll
                for (int g = 0; g < 4; ++g) acc[jj][g] = 0.0f;
#pragma unroll
            for (int k = 0; k < 16; ++k) {
                unsigned hv = hs2[lane + 64 * k];
#pragma unroll
                for (int jj = 0; jj < 2; ++jj)
#pragma unroll
                    for (int g = 0; g < 4; ++g)
                        acc[jj][g] = dot2acc(w2[jj][g][k], hv, acc[jj][g]);
            }
            __syncthreads();

#pragma unroll
            for (int off = 32; off >= 1; off >>= 1)
#pragma unroll
                for (int jj = 0; jj < 2; ++jj)
#pragma unroll
                    for (int g = 0; g < 4; ++g)
                        acc[jj][g] += __shfl_xor(acc[jj][g], off);

#pragma unroll
            for (int jj = 0; jj < 2; ++jj) {
                float gi = sigmoidf_(acc[jj][0] + bs[jj][0]);
                float gf = sigmoidf_(acc[jj][1] + bs[jj][1]);
                float gg = tanhf_   (acc[jj][2] + bs[jj][2]);
                float go = sigmoidf_(acc[jj][3] + bs[jj][3]);
                cst[jj] = gf * cst[jj] + gi * gg;
                hcur[jj] = go * tanhf_(cst[jj]);
            }
            if (lane == 0) {
                unsigned long long tw = ((unsigned long long)(t + 1)) << 32;
                __hip_atomic_store(&h1pkt[(size_t)t * 512 + (j0 >> 1)],
                                   tw | pack2(hcur[0], hcur[1]),
                                   __ATOMIC_RELAXED, __HIP_MEMORY_SCOPE_AGENT);
                float2 o2 = make_float2(fmaxf(hcur[0], 0.0f), fmaxf(hcur[1], 0.0f));
                *(float2*)(out + (size_t)t * Hn + j0) = o2;   // outputs[t] = relu(h1)
            }
        }
        if (lane == 0) {
#pragma unroll
            for (int jj = 0; jj < 2; ++jj) {
                out[OUTS + Hn + j0 + jj] = hcur[jj];           // hf layer 1
                out[OUTS + 3 * Hn + j0 + jj] = cst[jj];        // cf layer 1
            }
        }
    }
}

extern "C" void kernel_launch(void* const* d_in, const int* in_sizes, int n_in,
                              void* d_out, int out_size, void* d_ws, size_t ws_size,
                              hipStream_t stream) {
    const float* x        = (const float*)d_in[0];
    const int*   ip       = (const int*)d_in[1];
    const int*   port     = (const int*)d_in[2];
    const float* hidden   = (const float*)d_in[3];
    const float* cell     = (const float*)d_in[4];
    const float* ip_emb   = (const float*)d_in[5];
    const float* port_emb = (const float*)d_in[6];
    const float* Wih0     = (const float*)d_in[7];
    const float* Whh0     = (const float*)d_in[8];
    const float* bih0     = (const float*)d_in[9];
    const float* bhh0     = (const float*)d_in[10];
    const float* Wih1     = (const float*)d_in[11];
    const float* Whh1     = (const float*)d_in[12];
    const float* bih1     = (const float*)d_in[13];
    const float* bhh1     = (const float*)d_in[14];
    float* out = (float*)d_out;

    // ws layout: h0pkt (4096x512 u64) | h1pkt (4096x512 u64) | xin (4096x33 f32)
    // = 16.8 + 16.8 + 0.54 MB. Tags are t+1 in the high 32 bits; the 0xAA
    // poison never matches, so no zeroing pass is needed.
    unsigned long long* h0pkt = (unsigned long long*)d_ws;
    unsigned long long* h1pkt = h0pkt + (size_t)Bn * 512;
    float* xin = (float*)(h1pkt + (size_t)Bn * 512);

    prep_kernel<<<dim3((Bn * INW + 255) / 256), dim3(256), 0, stream>>>(
        x, ip, port, ip_emb, port_emb, xin);

    lstm_kernel<<<dim3(96), dim3(TPB), 0, stream>>>(
        xin, hidden, cell, Wih0, Whh0, bih0, bhh0, Wih1, Whh1, bih1, bhh1,
        out, h0pkt, h1pkt);
}

// Round 3
// 23094.997 us; speedup vs baseline: 3.2041x; 1.0019x over previous
//
#include <hip/hip_runtime.h>
#include <hip/hip_fp16.h>
#include <math.h>

#define Hn 1024
#define Bn 4096
#define INW 33
#define OUTS (Bn * Hn)
#define TPB 512

typedef _Float16 half2v __attribute__((ext_vector_type(2)));
typedef unsigned uint4v __attribute__((ext_vector_type(4)));

__device__ __forceinline__ float sigmoidf_(float x) {
    return 1.0f / (1.0f + __expf(-x));
}
__device__ __forceinline__ float tanhf_(float x) {
    float e = __expf(-2.0f * fabsf(x));
    float r = (1.0f - e) / (1.0f + e);
    return copysignf(r, x);
}
__device__ __forceinline__ unsigned pack2(float a, float b) {
    __half2 h = __floats2half2_rn(a, b);
    return __builtin_bit_cast(unsigned, h);
}
__device__ __forceinline__ float dot2acc(unsigned w, unsigned hv, float acc) {
#if __has_builtin(__builtin_amdgcn_fdot2)
    return __builtin_amdgcn_fdot2(__builtin_bit_cast(half2v, w),
                                  __builtin_bit_cast(half2v, hv), acc, false);
#else
    __half2 wh = __builtin_bit_cast(__half2, w);
    __half2 hh = __builtin_bit_cast(__half2, hv);
    float2 wf = __half22float2(wh), hf = __half22float2(hh);
    return acc + wf.x * hf.x + wf.y * hf.y;
#endif
}

// Wave-coalesced poll of one 512-packet row (4 KB). Lane i owns the 16 B at
// row + 16*i (packets 2i, 2i+1 of each 128-packet stripe); 4 strided dwordx4
// loads cover the row in 64 cache-line transactions (vs 512 uncoalesced
// atomics in R2). sc0 sc1 = device-coherent (bypass L1/L2, read LLC).
// Each 8B packet = [data half2 | tag]; written by a single atomic dwordx2
// store, so tag/data within a packet cannot tear.
__device__ __forceinline__ void poll_row(const unsigned long long* rowbase, int lane,
                                         unsigned tag, uint4v& r0, uint4v& r1,
                                         uint4v& r2, uint4v& r3) {
    const char* p = (const char*)rowbase + lane * 16;
    int rounds = 0;
    for (;;) {
        asm volatile(
            "global_load_dwordx4 %0, %4, off sc0 sc1\n\t"
            "global_load_dwordx4 %1, %4, off offset:1024 sc0 sc1\n\t"
            "global_load_dwordx4 %2, %4, off offset:2048 sc0 sc1\n\t"
            "global_load_dwordx4 %3, %4, off offset:3072 sc0 sc1\n\t"
            "s_waitcnt vmcnt(0)"
            : "=v"(r0), "=v"(r1), "=v"(r2), "=v"(r3)
            : "v"(p)
            : "memory");
        bool ok = (r0.y == tag) & (r0.w == tag) & (r1.y == tag) & (r1.w == tag)
                & (r2.y == tag) & (r2.w == tag) & (r3.y == tag) & (r3.w == tag);
        if (__all(ok)) break;
        if (++rounds > (1 << 22)) break;  // bailout: wrong answer beats a wedged GPU
    }
}

// deposit a polled row into LDS at hs2[base .. base+511]
__device__ __forceinline__ void row_to_lds(unsigned* hs2, int base, int lane,
                                           const uint4v& r0, const uint4v& r1,
                                           const uint4v& r2, const uint4v& r3) {
    hs2[base +       2 * lane]     = r0.x;  hs2[base +       2 * lane + 1] = r0.z;
    hs2[base + 128 + 2 * lane]     = r1.x;  hs2[base + 128 + 2 * lane + 1] = r1.z;
    hs2[base + 256 + 2 * lane]     = r2.x;  hs2[base + 256 + 2 * lane + 1] = r2.z;
    hs2[base + 384 + 2 * lane]     = r3.x;  hs2[base + 384 + 2 * lane + 1] = r3.z;
}

// xin = [x | ip_emb[ip] | port_emb[port]]  (4096 x 33)
__global__ void prep_kernel(const float* __restrict__ x, const int* __restrict__ ip,
                            const int* __restrict__ port, const float* __restrict__ ip_emb,
                            const float* __restrict__ port_emb, float* __restrict__ xin) {
    int gid = blockIdx.x * blockDim.x + threadIdx.x;
    if (gid < Bn * INW) {
        int t = gid / INW;
        int k = gid - t * INW;
        float v;
        if (k < 17) {
            v = x[t * 17 + k];
        } else if (k < 25) {
            v = ip_emb[ip[t * 8 + (k - 17)]];
        } else {
            int kk = k - 25;
            v = port_emb[port[t * 2 + (kk >> 2)] * 4 + (kk & 3)];
        }
        xin[gid] = v;
    }
}

__global__ void __launch_bounds__(TPB, 2) lstm_kernel(
    const float* __restrict__ xin,
    const float* __restrict__ hid0, const float* __restrict__ cel0,
    const float* __restrict__ Wih0, const float* __restrict__ Whh0,
    const float* __restrict__ bih0, const float* __restrict__ bhh0,
    const float* __restrict__ Wih1, const float* __restrict__ Whh1,
    const float* __restrict__ bih1, const float* __restrict__ bhh1,
    float* __restrict__ out,
    unsigned long long* __restrict__ h0pkt,   // [4096][512] : tag|h0 pair
    unsigned long long* __restrict__ h1pkt)   // [4096][512] : tag|h1 pair
{
    __shared__ unsigned hs2[1024];   // half2 chunks of the input vector(s)
    const int tid  = threadIdx.x;
    const int lane = tid & 63;
    const int wave = tid >> 6;
    const int bx   = blockIdx.x;

    if (bx < 32) {
        // ================= layer 0 : 32 blocks, wave owns 4 h-indices ========
        const int j0 = bx * 32 + wave * 4;
        unsigned w2[4][4][8];     // f16-pair weights of Whh0
        float    wx[4][4];        // fp32 x-weights (lane < 33)
        float    bs[4][4];
#pragma unroll
        for (int jj = 0; jj < 4; ++jj) {
#pragma unroll
            for (int g = 0; g < 4; ++g) {
                const int row = g * Hn + (j0 + jj);
                const float* wr = Whh0 + (size_t)row * Hn;
#pragma unroll
                for (int k = 0; k < 8; ++k) {
                    int c = lane + 64 * k;
                    w2[jj][g][k] = pack2(wr[2 * c], wr[2 * c + 1]);
                }
                wx[jj][g] = (lane < INW) ? Wih0[row * INW + lane] : 0.0f;
                bs[jj][g] = bih0[row] + bhh0[row];
            }
        }
        float cst[4], hcur[4];
#pragma unroll
        for (int jj = 0; jj < 4; ++jj) { cst[jj] = cel0[j0 + jj]; hcur[jj] = 0.0f; }

        for (int t = 0; t < Bn; ++t) {
            float xv = xin[t * INW + (lane < INW ? lane : 0)];  // prefetch (L2-hot)
            if (wave == 0) {
                if (t == 0) {
#pragma unroll
                    for (int m = 0; m < 8; ++m) {
                        int q = lane + 64 * m;
                        hs2[q] = pack2(hid0[2 * q], hid0[2 * q + 1]);
                    }
                } else {
                    uint4v r0, r1, r2, r3;
                    poll_row(h0pkt + (size_t)(t - 1) * 512, lane, (unsigned)t, r0, r1, r2, r3);
                    row_to_lds(hs2, 0, lane, r0, r1, r2, r3);
                }
            }
            __syncthreads();

            float acc[4][4];
#pragma unroll
            for (int jj = 0; jj < 4; ++jj)
#pragma unroll
                for (int g = 0; g < 4; ++g) acc[jj][g] = wx[jj][g] * xv;
#pragma unroll
            for (int k = 0; k < 8; ++k) {
                unsigned hv = hs2[lane + 64 * k];   // 2-way bank alias: free
#pragma unroll
                for (int jj = 0; jj < 4; ++jj)
#pragma unroll
                    for (int g = 0; g < 4; ++g)
                        acc[jj][g] = dot2acc(w2[jj][g][k], hv, acc[jj][g]);
            }
            __syncthreads();   // hs2 reads done; next iter may overwrite

#pragma unroll
            for (int off = 32; off >= 1; off >>= 1)
#pragma unroll
                for (int jj = 0; jj < 4; ++jj)
#pragma unroll
                    for (int g = 0; g < 4; ++g)
                        acc[jj][g] += __shfl_xor(acc[jj][g], off);

#pragma unroll
            for (int jj = 0; jj < 4; ++jj) {
                float gi = sigmoidf_(acc[jj][0] + bs[jj][0]);
                float gf = sigmoidf_(acc[jj][1] + bs[jj][1]);
                float gg = tanhf_   (acc[jj][2] + bs[jj][2]);
                float go = sigmoidf_(acc[jj][3] + bs[jj][3]);
                cst[jj] = gf * cst[jj] + gi * gg;
                hcur[jj] = go * tanhf_(cst[jj]);
            }
            if (lane == 0) {
                unsigned long long tw = ((unsigned long long)(t + 1)) << 32;
                __hip_atomic_store(&h0pkt[(size_t)t * 512 + (j0 >> 1)],
                                   tw | pack2(hcur[0], hcur[1]),
                                   __ATOMIC_RELAXED, __HIP_MEMORY_SCOPE_AGENT);
                __hip_atomic_store(&h0pkt[(size_t)t * 512 + (j0 >> 1) + 1],
                                   tw | pack2(hcur[2], hcur[3]),
                                   __ATOMIC_RELAXED, __HIP_MEMORY_SCOPE_AGENT);
            }
        }
        if (lane == 0) {
#pragma unroll
            for (int jj = 0; jj < 4; ++jj) {
                out[OUTS + j0 + jj] = hcur[jj];            // hf layer 0
                out[OUTS + 2 * Hn + j0 + jj] = cst[jj];    // cf layer 0
            }
        }
    } else {
        // ================= layer 1 : 64 blocks, wave owns 2 h-indices ========
        const int blk = bx - 32;
        const int j0  = blk * 16 + wave * 2;
        unsigned w2[2][4][16];    // k<8: Wih1 (vs h0[t]) ; k>=8: Whh1 (vs h1[t-1])
        float    bs[2][4];
#pragma unroll
        for (int jj = 0; jj < 2; ++jj) {
#pragma unroll
            for (int g = 0; g < 4; ++g) {
                const int row = g * Hn + (j0 + jj);
                const float* wr1 = Wih1 + (size_t)row * Hn;
                const float* wr2 = Whh1 + (size_t)row * Hn;
#pragma unroll
                for (int k = 0; k < 8; ++k) {
                    int c = lane + 64 * k;
                    w2[jj][g][k]     = pack2(wr1[2 * c], wr1[2 * c + 1]);
                    w2[jj][g][8 + k] = pack2(wr2[2 * c], wr2[2 * c + 1]);
                }
                bs[jj][g] = bih1[row] + bhh1[row];
            }
        }
        float cst[2], hcur[2];
#pragma unroll
        for (int jj = 0; jj < 2; ++jj) { cst[jj] = cel0[Hn + j0 + jj]; hcur[jj] = 0.0f; }

        for (int t = 0; t < Bn; ++t) {
            if (wave == 0) {
                uint4v r0, r1, r2, r3;
                poll_row(h0pkt + (size_t)t * 512, lane, (unsigned)(t + 1), r0, r1, r2, r3);
                row_to_lds(hs2, 0, lane, r0, r1, r2, r3);          // h0[t]
            } else if (wave == 1) {
                if (t == 0) {
#pragma unroll
                    for (int m = 0; m < 8; ++m) {
                        int q = lane + 64 * m;
                        hs2[512 + q] = pack2(hid0[Hn + 2 * q], hid0[Hn + 2 * q + 1]);
                    }
                } else {
                    uint4v r0, r1, r2, r3;
                    poll_row(h1pkt + (size_t)(t - 1) * 512, lane, (unsigned)t, r0, r1, r2, r3);
                    row_to_lds(hs2, 512, lane, r0, r1, r2, r3);    // h1[t-1]
                }
            }
            __syncthreads();

            float acc[2][4];
#pragma unroll
            for (int jj = 0; jj < 2; ++jj)
#pragma unroll
                for (int g = 0; g < 4; ++g) acc[jj][g] = 0.0f;
#pragma unroll
            for (int k = 0; k < 16; ++k) {
                unsigned hv = hs2[lane + 64 * k];
#pragma unroll
                for (int jj = 0; jj < 2; ++jj)
#pragma unroll
                    for (int g = 0; g < 4; ++g)
                        acc[jj][g] = dot2acc(w2[jj][g][k], hv, acc[jj][g]);
            }
            __syncthreads();

#pragma unroll
            for (int off = 32; off >= 1; off >>= 1)
#pragma unroll
                for (int jj = 0; jj < 2; ++jj)
#pragma unroll
                    for (int g = 0; g < 4; ++g)
                        acc[jj][g] += __shfl_xor(acc[jj][g], off);

#pragma unroll
            for (int jj = 0; jj < 2; ++jj) {
                float gi = sigmoidf_(acc[jj][0] + bs[jj][0]);
                float gf = sigmoidf_(acc[jj][1] + bs[jj][1]);
                float gg = tanhf_   (acc[jj][2] + bs[jj][2]);
                float go = sigmoidf_(acc[jj][3] + bs[jj][3]);
                cst[jj] = gf * cst[jj] + gi * gg;
                hcur[jj] = go * tanhf_(cst[jj]);
            }
            if (lane == 0) {
                unsigned long long tw = ((unsigned long long)(t + 1)) << 32;
                __hip_atomic_store(&h1pkt[(size_t)t * 512 + (j0 >> 1)],
                                   tw | pack2(hcur[0], hcur[1]),
                                   __ATOMIC_RELAXED, __HIP_MEMORY_SCOPE_AGENT);
                float2 o2 = make_float2(fmaxf(hcur[0], 0.0f), fmaxf(hcur[1], 0.0f));
                *(float2*)(out + (size_t)t * Hn + j0) = o2;   // outputs[t] = relu(h1)
            }
        }
        if (lane == 0) {
#pragma unroll
            for (int jj = 0; jj < 2; ++jj) {
                out[OUTS + Hn + j0 + jj] = hcur[jj];           // hf layer 1
                out[OUTS + 3 * Hn + j0 + jj] = cst[jj];        // cf layer 1
            }
        }
    }
}

extern "C" void kernel_launch(void* const* d_in, const int* in_sizes, int n_in,
                              void* d_out, int out_size, void* d_ws, size_t ws_size,
                              hipStream_t stream) {
    const float* x        = (const float*)d_in[0];
    const int*   ip       = (const int*)d_in[1];
    const int*   port     = (const int*)d_in[2];
    const float* hidden   = (const float*)d_in[3];
    const float* cell     = (const float*)d_in[4];
    const float* ip_emb   = (const float*)d_in[5];
    const float* port_emb = (const float*)d_in[6];
    const float* Wih0     = (const float*)d_in[7];
    const float* Whh0     = (const float*)d_in[8];
    const float* bih0     = (const float*)d_in[9];
    const float* bhh0     = (const float*)d_in[10];
    const float* Wih1     = (const float*)d_in[11];
    const float* Whh1     = (const float*)d_in[12];
    const float* bih1     = (const float*)d_in[13];
    const float* bhh1     = (const float*)d_in[14];
    float* out = (float*)d_out;

    // ws layout: h0pkt (4096x512 u64) | h1pkt (4096x512 u64) | xin (4096x33 f32)
    // Tags are t+1 in the high 32 bits; the 0xAA poison never matches, so no
    // zeroing pass is needed.
    unsigned long long* h0pkt = (unsigned long long*)d_ws;
    unsigned long long* h1pkt = h0pkt + (size_t)Bn * 512;
    float* xin = (float*)(h1pkt + (size_t)Bn * 512);

    prep_kernel<<<dim3((Bn * INW + 255) / 256), dim3(256), 0, stream>>>(
        x, ip, port, ip_emb, port_emb, xin);

    lstm_kernel<<<dim3(96), dim3(TPB), 0, stream>>>(
        xin, hidden, cell, Wih0, Whh0, bih0, bhh0, Wih1, Whh1, bih1, bhh1,
        out, h0pkt, h1pkt);
}